// Round 1
// baseline (1248.496 us; speedup 1.0000x reference)
//
#include <hip/hip_runtime.h>
#include <stdint.h>

// Problem constants (from reference setup_inputs)
#define N_NODES 50000
#define CIN 128
#define CMID 128
#define COUT 32
#define KNB 27
#define EPSV 1e-5f

typedef __attribute__((ext_vector_type(4))) float f4v;
typedef __attribute__((ext_vector_type(8))) short s8v;
typedef __attribute__((ext_vector_type(4))) short s4v;

__device__ __forceinline__ unsigned short f2bf(float f) {
  union { float f; uint32_t u; } v; v.f = f;
  return (unsigned short)((v.u + 0x7FFFu + ((v.u >> 16) & 1u)) >> 16);  // RNE
}

// async global->LDS, 16B per lane. Dest is wave-uniform base + lane*16 (HW rule).
__device__ __forceinline__ void gload_lds16(const void* g, void* lds) {
  __builtin_amdgcn_global_load_lds(
      (const __attribute__((address_space(1))) uint32_t*)(uintptr_t)g,
      (__attribute__((address_space(3))) uint32_t*)(uint32_t)(uintptr_t)lds,
      16, 0, 0);
}

__device__ __forceinline__ f4v mfma16(s8v a, s8v b, f4v c) {
  return __builtin_amdgcn_mfma_f32_16x16x32_bf16(a, b, c, 0, 0, 0);
}

// ---------------------------------------------------------------- prep ------
// xb[(N+1)][128] bf16 (row N = zeros for empty neighbors)
// wt1[k][d][c] = bf16(W1[k][c][d])   (B^T layout: contiguous along cin)
// wt2[k][d][c] = bf16(W2[k][c][d])
// gsums[0..63] = 0 ; flag = (neigh is int64?)
__global__ __launch_bounds__(256) void k_prep(
    const float* __restrict__ data, const float* __restrict__ W1,
    const float* __restrict__ W2, const int* __restrict__ neigh_raw,
    short* __restrict__ xb, short* __restrict__ wt1, short* __restrict__ wt2,
    float* __restrict__ gsums, int* __restrict__ flag)
{
  int gtid = blockIdx.x * 256 + threadIdx.x;
  int stride = gridDim.x * 256;
  const int TOT0 = (N_NODES + 1) * (CIN / 4);       // xb in float4 chunks
  const int TOT1 = KNB * CMID * CIN;                // wt1 elements
  const int TOT2 = KNB * COUT * CMID;               // wt2 elements
  for (int i = gtid; i < TOT0 + TOT1 + TOT2; i += stride) {
    if (i < TOT0) {
      int row = i >> 5, c4 = i & 31;
      s4v o = {};
      if (row < N_NODES) {
        f4v v = *(const f4v*)(data + row * CIN + c4 * 4);
        o[0] = (short)f2bf(v[0]); o[1] = (short)f2bf(v[1]);
        o[2] = (short)f2bf(v[2]); o[3] = (short)f2bf(v[3]);
      }
      *(s4v*)(xb + row * CIN + c4 * 4) = o;
    } else if (i < TOT0 + TOT1) {
      int o = i - TOT0;
      int k = o >> 14, rem = o & 16383, d = rem >> 7, c = rem & 127;
      wt1[o] = (short)f2bf(W1[(k << 14) + (c << 7) + d]);
    } else {
      int o = i - TOT0 - TOT1;
      int k = o >> 12, rem = o & 4095, d = rem >> 7, c = rem & 127;
      wt2[o] = (short)f2bf(W2[(k * 128 + c) * 32 + d]);
    }
  }
  if (gtid < 64) gsums[gtid] = 0.0f;
  if (gtid == 0) {
    // int64 detection: hi words of first 16 entries all 0 / -1
    int ok = 1;
    for (int i = 0; i < 16; ++i) {
      int hi = neigh_raw[2 * i + 1];
      if (hi != 0 && hi != -1) ok = 0;
    }
    *flag = ok;
  }
}

// ---------------------------------------------------------------- conv1 -----
// 64x128 tile, 4 waves (wave w owns cols [32w,32w+32)), K=27x128.
// A staged via global_load_lds (linear dest + inverse-swizzled SOURCE,
// swizzle byte ^= (row&7)<<4 re-applied on ds_read) -> ~2-way conflicts.
__global__ __launch_bounds__(256) void k_conv1(
    const short* __restrict__ xb, const void* __restrict__ neigh,
    const short* __restrict__ wt1, const float* __restrict__ b1,
    float* __restrict__ x1, float* __restrict__ gsum,
    float* __restrict__ gsumsq, const int* __restrict__ flag)
{
  __shared__ short at[2][64 * CIN];   // 2 x 16KB
  __shared__ int nidx[64][KNB];       // 6.9KB
  const int tid = threadIdx.x;
  const int l = tid & 63;
  const int w = tid >> 6;
  const int m0 = blockIdx.x * 64;
  const bool is64 = (*flag != 0);

  for (int f = tid; f < 64 * KNB; f += 256) {
    int r = f / KNB, k = f - r * KNB;
    int grow = m0 + r; if (grow >= N_NODES) grow = N_NODES - 1;
    long long v = is64 ? ((const long long*)neigh)[grow * KNB + k]
                       : (long long)((const int*)neigh)[grow * KNB + k];
    nidx[r][k] = (v < 0) ? N_NODES : (int)v;
  }
  __syncthreads();

  auto stage = [&](int buf, int k) {
#pragma unroll
    for (int p = 0; p < 4; ++p) {
      int r = p * 16 + w * 4 + (l >> 4);          // row 0..63
      int slot = l & 15;                          // 16B slot in row
      int idx = nidx[r][k];
      const short* src = xb + idx * CIN + ((slot * 8) ^ ((r & 7) << 3));
      short* dst = &at[buf][(p * 256 + w * 64) * 8];   // wave-uniform base
      gload_lds16(src, dst);
    }
  };

  f4v acc[4][2] = {};
  stage(0, 0);
  __syncthreads();
  int cur = 0;
  for (int k = 0; k < KNB; ++k) {
    if (k + 1 < KNB) stage(cur ^ 1, k + 1);       // async prefetch next k
    const short* wb = wt1 + k * (CMID * CIN);
#pragma unroll
    for (int kc = 0; kc < 4; ++kc) {
      s8v bf0 = *(const s8v*)(wb + (w * 32 + (l & 15)) * CIN + kc * 32 + (l >> 4) * 8);
      s8v bf1 = *(const s8v*)(wb + (w * 32 + 16 + (l & 15)) * CIN + kc * 32 + (l >> 4) * 8);
#pragma unroll
      for (int m = 0; m < 4; ++m) {
        int row = m * 16 + (l & 15);
        s8v af = *(const s8v*)(&at[cur][row * CIN + ((kc * 32 + (l >> 4) * 8) ^ ((row & 7) << 3))]);
        acc[m][0] = mfma16(af, bf0, acc[m][0]);
        acc[m][1] = mfma16(af, bf1, acc[m][1]);
      }
    }
    __syncthreads();   // drains stage loads (vmcnt0) + guards LDS reuse
    cur ^= 1;
  }

  // epilogue: +b1, store x1, per-column sums -> group atomics
  float s[2] = {0.f, 0.f}, ss[2] = {0.f, 0.f};
#pragma unroll
  for (int n = 0; n < 2; ++n) {
    int col = w * 32 + n * 16 + (l & 15);
    float bias = b1[col];
#pragma unroll
    for (int m = 0; m < 4; ++m) {
#pragma unroll
      for (int j = 0; j < 4; ++j) {
        int grow = m0 + m * 16 + (l >> 4) * 4 + j;
        if (grow < N_NODES) {
          float v = acc[m][n][j] + bias;
          x1[grow * CMID + col] = v;
          s[n] += v; ss[n] += v * v;
        }
      }
    }
  }
#pragma unroll
  for (int n = 0; n < 2; ++n) {
    s[n] += __shfl_xor(s[n], 16);  s[n] += __shfl_xor(s[n], 32);
    ss[n] += __shfl_xor(ss[n], 16); ss[n] += __shfl_xor(ss[n], 32);
    if (l < 16) {
      int col = w * 32 + n * 16 + l;
      atomicAdd(&gsum[col >> 2], s[n]);
      atomicAdd(&gsumsq[col >> 2], ss[n]);
    }
  }
}

// ---------------------------------------------------------------- GN+SiLU ---
__global__ __launch_bounds__(256) void k_gnsilu(
    const float* __restrict__ x1, const float* __restrict__ gsums,
    const float* __restrict__ gn_w, const float* __restrict__ gn_b,
    short* __restrict__ xnb)
{
  const float invc = 1.0f / (N_NODES * 4.0f);   // group = 4 channels x N nodes
  int gtid = blockIdx.x * 256 + threadIdx.x;
  int stride = gridDim.x * 256;
  const int TOT = (N_NODES + 1) * (CMID / 4);   // float4 chunk == one group slice
  for (int i = gtid; i < TOT; i += stride) {
    int row = i >> 5, g = i & 31;
    s4v o = {};
    if (row < N_NODES) {
      float mean = gsums[g] * invc;
      float var = gsums[32 + g] * invc - mean * mean;
      float rs = rsqrtf(var + EPSV);
      f4v v = *(const f4v*)(x1 + row * CMID + g * 4);
      f4v wv = *(const f4v*)(gn_w + g * 4);
      f4v bv = *(const f4v*)(gn_b + g * 4);
#pragma unroll
      for (int e = 0; e < 4; ++e) {
        float xn = (v[e] - mean) * rs * wv[e] + bv[e];
        float y = xn / (1.0f + __expf(-xn));     // SiLU
        o[e] = (short)f2bf(y);
      }
    }
    *(s4v*)(xnb + row * CMID + g * 4) = o;       // row N stays zeros
  }
}

// ---------------------------------------------------------------- conv2 -----
// 128x32 tile, 4 waves (wave w owns rows [32w,32w+32)), all 32 cols.
__global__ __launch_bounds__(256) void k_conv2(
    const short* __restrict__ xnb, const void* __restrict__ neigh,
    const short* __restrict__ wt2, const float* __restrict__ b2,
    float* __restrict__ out, const int* __restrict__ flag)
{
  __shared__ short at[2][128 * CMID];   // 2 x 32KB
  __shared__ int nidx[128][KNB];        // 13.8KB
  const int tid = threadIdx.x;
  const int l = tid & 63;
  const int w = tid >> 6;
  const int m0 = blockIdx.x * 128;
  const bool is64 = (*flag != 0);

  for (int f = tid; f < 128 * KNB; f += 256) {
    int r = f / KNB, k = f - r * KNB;
    int grow = m0 + r; if (grow >= N_NODES) grow = N_NODES - 1;
    long long v = is64 ? ((const long long*)neigh)[grow * KNB + k]
                       : (long long)((const int*)neigh)[grow * KNB + k];
    nidx[r][k] = (v < 0) ? N_NODES : (int)v;
  }
  __syncthreads();

  auto stage = [&](int buf, int k) {
#pragma unroll
    for (int p = 0; p < 8; ++p) {
      int r = p * 16 + w * 4 + (l >> 4);          // row 0..127
      int slot = l & 15;
      int idx = nidx[r][k];
      const short* src = xnb + idx * CMID + ((slot * 8) ^ ((r & 7) << 3));
      short* dst = &at[buf][(p * 256 + w * 64) * 8];
      gload_lds16(src, dst);
    }
  };

  f4v acc[2][2] = {};
  stage(0, 0);
  __syncthreads();
  int cur = 0;
  for (int k = 0; k < KNB; ++k) {
    if (k + 1 < KNB) stage(cur ^ 1, k + 1);
    const short* wb = wt2 + k * (COUT * CMID);
#pragma unroll
    for (int kc = 0; kc < 4; ++kc) {
      s8v bf0 = *(const s8v*)(wb + ((l & 15)) * CMID + kc * 32 + (l >> 4) * 8);
      s8v bf1 = *(const s8v*)(wb + (16 + (l & 15)) * CMID + kc * 32 + (l >> 4) * 8);
#pragma unroll
      for (int m = 0; m < 2; ++m) {
        int row = w * 32 + m * 16 + (l & 15);
        s8v af = *(const s8v*)(&at[cur][row * CMID + ((kc * 32 + (l >> 4) * 8) ^ ((row & 7) << 3))]);
        acc[m][0] = mfma16(af, bf0, acc[m][0]);
        acc[m][1] = mfma16(af, bf1, acc[m][1]);
      }
    }
    __syncthreads();
    cur ^= 1;
  }

#pragma unroll
  for (int n = 0; n < 2; ++n) {
    int col = n * 16 + (l & 15);
    float bias = b2[col];
#pragma unroll
    for (int m = 0; m < 2; ++m) {
#pragma unroll
      for (int j = 0; j < 4; ++j) {
        int grow = m0 + w * 32 + m * 16 + (l >> 4) * 4 + j;
        if (grow < N_NODES) out[grow * COUT + col] = acc[m][n][j] + bias;
      }
    }
  }
}

// ---------------------------------------------------------------- launch ----
extern "C" void kernel_launch(void* const* d_in, const int* in_sizes, int n_in,
                              void* d_out, int out_size, void* d_ws, size_t ws_size,
                              hipStream_t stream) {
  const float* data = (const float*)d_in[0];
  const void* neigh = d_in[1];                    // int32 or int64, detected
  const float* W1   = (const float*)d_in[2];
  const float* b1   = (const float*)d_in[3];
  const float* gn_w = (const float*)d_in[4];
  const float* gn_b = (const float*)d_in[5];
  const float* W2   = (const float*)d_in[6];
  const float* b2   = (const float*)d_in[7];

  char* p = (char*)d_ws;
  short* xb   = (short*)p; p += (size_t)(N_NODES + 1) * CIN * 2;    // 12.8MB
  short* wt1  = (short*)p; p += (size_t)KNB * CMID * CIN * 2;       // 884KB
  short* wt2  = (short*)p; p += (size_t)KNB * COUT * CMID * 2;      // 221KB
  float* x1   = (float*)p; p += (size_t)N_NODES * CMID * 4;         // 25.6MB
  short* xnb  = (short*)p; p += (size_t)(N_NODES + 1) * CMID * 2;   // 12.8MB
  float* gsums = (float*)p;                                          // 64 f32 + flag
  int* flag = (int*)(gsums + 64);

  k_prep<<<2048, 256, 0, stream>>>(data, W1, W2, (const int*)neigh,
                                   xb, wt1, wt2, gsums, flag);
  k_conv1<<<(N_NODES + 63) / 64, 256, 0, stream>>>(xb, neigh, wt1, b1, x1,
                                                   gsums, gsums + 32, flag);
  k_gnsilu<<<3126, 256, 0, stream>>>(x1, gsums, gn_w, gn_b, xnb);
  k_conv2<<<(N_NODES + 127) / 128, 256, 0, stream>>>(xnb, neigh, wt2, b2,
                                                     (float*)d_out, flag);
}

// Round 2
// 356.135 us; speedup vs baseline: 3.5057x; 3.5057x over previous
//
#include <hip/hip_runtime.h>
#include <stdint.h>

#define N_NODES 50000
#define CIN 128
#define CMID 128
#define COUT 32
#define KNB 27
#define EPSV 1e-5f

typedef __attribute__((ext_vector_type(4))) float f4v;
typedef __attribute__((ext_vector_type(8))) short s8v;
typedef __attribute__((ext_vector_type(4))) short s4v;

__device__ __forceinline__ unsigned short f2bf(float f) {
  union { float f; uint32_t u; } v; v.f = f;
  return (unsigned short)((v.u + 0x7FFFu + ((v.u >> 16) & 1u)) >> 16);  // RNE
}

__device__ __forceinline__ f4v mfma16(s8v a, s8v b, f4v c) {
  return __builtin_amdgcn_mfma_f32_16x16x32_bf16(a, b, c, 0, 0, 0);
}

// neighbor index fetch, int32/int64 auto, OOB/empty -> zero row N_NODES
__device__ __forceinline__ int read_idx(const void* neigh, int row, int k, bool is64) {
  if (row >= N_NODES) return N_NODES;
  long long v = is64 ? ((const long long*)neigh)[(size_t)row * KNB + k]
                     : (long long)((const int*)neigh)[(size_t)row * KNB + k];
  return (v < 0) ? N_NODES : (int)v;
}

// ---------------------------------------------------------------- prep ------
// xb[(N+1)][128] bf16 (row N zeros); wt1f/wt2f in MFMA B-fragment order:
//   wt1f chunk ((k*4+kc)*8+n)*64+l  = 8 bf16 {W1[k][kc*32+(l>>4)*8+e][n*16+(l&15)]}
//   wt2f chunk ((k*4+kc)*2+n)*64+l  = 8 bf16 {W2[k][kc*32+(l>>4)*8+e][n*16+(l&15)]}
// gsums[0..63]=0; flag = neigh-is-int64
__global__ __launch_bounds__(256) void k_prep(
    const float* __restrict__ data, const float* __restrict__ W1,
    const float* __restrict__ W2, const int* __restrict__ neigh_raw,
    short* __restrict__ xb, short* __restrict__ wt1f, short* __restrict__ wt2f,
    float* __restrict__ gsums, int* __restrict__ flag)
{
  const int TOT0 = (N_NODES + 1) * (CIN / 4);   // xb s4v chunks
  const int TOTW1 = KNB * 4 * 8 * 64;           // wt1f 16B chunks
  const int TOTW2 = KNB * 4 * 2 * 64;           // wt2f 16B chunks
  int gtid = blockIdx.x * 256 + threadIdx.x;
  int stride = gridDim.x * 256;
  for (int i = gtid; i < TOT0 + TOTW1 + TOTW2; i += stride) {
    if (i < TOT0) {
      int row = i >> 5, c4 = i & 31;
      s4v o = {};
      if (row < N_NODES) {
        f4v v = *(const f4v*)(data + (size_t)row * CIN + c4 * 4);
        o[0] = (short)f2bf(v[0]); o[1] = (short)f2bf(v[1]);
        o[2] = (short)f2bf(v[2]); o[3] = (short)f2bf(v[3]);
      }
      *(s4v*)(xb + (size_t)row * CIN + c4 * 4) = o;
    } else if (i < TOT0 + TOTW1) {
      int c = i - TOT0;
      int k = c >> 11, rem = c & 2047;
      int kc = rem >> 9, rem2 = rem & 511;
      int n = rem2 >> 6, l = rem2 & 63;
      int cin0 = kc * 32 + (l >> 4) * 8, cout = n * 16 + (l & 15);
      s8v o;
#pragma unroll
      for (int e = 0; e < 8; ++e)
        o[e] = (short)f2bf(W1[(size_t)k * (CIN * CMID) + (cin0 + e) * CMID + cout]);
      *(s8v*)(wt1f + (size_t)c * 8) = o;
    } else {
      int c = i - TOT0 - TOTW1;
      int k = c >> 9, rem = c & 511;
      int kc = rem >> 7, rem2 = rem & 127;
      int n = rem2 >> 6, l = rem2 & 63;
      int cin0 = kc * 32 + (l >> 4) * 8, cout = n * 16 + (l & 15);
      s8v o;
#pragma unroll
      for (int e = 0; e < 8; ++e)
        o[e] = (short)f2bf(W2[(size_t)k * (CMID * COUT) + (cin0 + e) * COUT + cout]);
      *(s8v*)(wt2f + (size_t)c * 8) = o;
    }
  }
  if (gtid < 64) gsums[gtid] = 0.0f;
  if (gtid == 0) {
    int ok = 1;
    for (int i = 0; i < 16; ++i) {
      int hi = neigh_raw[2 * i + 1];
      if (hi != 0 && hi != -1) ok = 0;
    }
    *flag = ok;
  }
}

// ---------------------------------------------------------------- conv1 -----
// No LDS, no barriers. Wave owns 32 rows x 128 cols, K split in 2 halves.
// Block = 4 waves = 128 rows. Grid = 391 rowblocks x 2 khalves.
__global__ __launch_bounds__(256) void k_conv1(
    const short* __restrict__ xb, const void* __restrict__ neigh,
    const short* __restrict__ wt1f, short* __restrict__ x1p,
    const int* __restrict__ flag)
{
  const int tid = threadIdx.x;
  const int l = tid & 63;
  const int w = tid >> 6;
  const int kh = (blockIdx.x >= 391) ? 1 : 0;
  const int rb = blockIdx.x - (kh ? 391 : 0);
  const int r0 = rb * 128 + w * 32;
  const bool is64 = (*flag != 0);
  const int k0 = kh ? 13 : 0, k1 = kh ? 27 : 13;

  f4v acc[2][8] = {};
  for (int k = k0; k < k1; ++k) {
    int i0 = read_idx(neigh, r0 + (l & 15), k, is64);
    int i1 = read_idx(neigh, r0 + 16 + (l & 15), k, is64);
    const short* a0p = xb + (size_t)i0 * CIN + (l >> 4) * 8;
    const short* a1p = xb + (size_t)i1 * CIN + (l >> 4) * 8;
    s8v a[2][4];
#pragma unroll
    for (int kc = 0; kc < 4; ++kc) {          // all 8 gathers in flight
      a[0][kc] = *(const s8v*)(a0p + kc * 32);
      a[1][kc] = *(const s8v*)(a1p + kc * 32);
    }
    const short* wp = wt1f + (size_t)k * 2048 * 8;
#pragma unroll
    for (int kc = 0; kc < 4; ++kc) {
#pragma unroll
      for (int n = 0; n < 8; ++n) {
        s8v b = *(const s8v*)(wp + ((kc * 8 + n) * 64 + l) * 8);  // coalesced 1KB
        acc[0][n] = mfma16(a[0][kc], b, acc[0][n]);
        acc[1][n] = mfma16(a[1][kc], b, acc[1][n]);
      }
    }
  }

  short* xp = x1p + (size_t)kh * N_NODES * CMID;
#pragma unroll
  for (int m = 0; m < 2; ++m) {
#pragma unroll
    for (int j = 0; j < 4; ++j) {
      int grow = r0 + m * 16 + (l >> 4) * 4 + j;
      if (grow < N_NODES) {
#pragma unroll
        for (int n = 0; n < 8; ++n)
          xp[(size_t)grow * CMID + n * 16 + (l & 15)] = (short)f2bf(acc[m][n][j]);
      }
    }
  }
}

// ---------------------------------------------------------------- sum -------
// group sums of x = p0 + p1 + b1 over all nodes (32 groups x 4 channels)
__global__ __launch_bounds__(256) void k_sum(
    const short* __restrict__ x1p, const float* __restrict__ b1,
    float* __restrict__ gsums)
{
  __shared__ float sh[64];
  const int tid = threadIdx.x;
  if (tid < 64) sh[tid] = 0.0f;
  __syncthreads();
  const int g = tid & 31;
  const short* p0 = x1p;
  const short* p1 = x1p + (size_t)N_NODES * CMID;
  f4v bv = *(const f4v*)(b1 + g * 4);
  float s = 0.f, ss = 0.f;
  for (int r = blockIdx.x * 8 + (tid >> 5); r < N_NODES; r += gridDim.x * 8) {
    s4v v0 = *(const s4v*)(p0 + (size_t)r * CMID + g * 4);
    s4v v1 = *(const s4v*)(p1 + (size_t)r * CMID + g * 4);
#pragma unroll
    for (int e = 0; e < 4; ++e) {
      float x = __uint_as_float(((uint32_t)(uint16_t)v0[e]) << 16) +
                __uint_as_float(((uint32_t)(uint16_t)v1[e]) << 16) + bv[e];
      s += x; ss += x * x;
    }
  }
  s += __shfl_xor(s, 32); ss += __shfl_xor(ss, 32);
  if ((tid & 32) == 0) { atomicAdd(&sh[g], s); atomicAdd(&sh[32 + g], ss); }
  __syncthreads();
  if (tid < 64) atomicAdd(&gsums[tid], sh[tid]);
}

// ---------------------------------------------------------------- GN+SiLU ---
__global__ __launch_bounds__(256) void k_gnsilu(
    const short* __restrict__ x1p, const float* __restrict__ b1,
    const float* __restrict__ gsums, const float* __restrict__ gn_w,
    const float* __restrict__ gn_b, short* __restrict__ xnb)
{
  const float invc = 1.0f / (N_NODES * 4.0f);
  const short* p0 = x1p;
  const short* p1 = x1p + (size_t)N_NODES * CMID;
  int gtid = blockIdx.x * 256 + threadIdx.x;
  int stride = gridDim.x * 256;
  const int TOT = (N_NODES + 1) * (CMID / 4);
  for (int i = gtid; i < TOT; i += stride) {
    int row = i >> 5, g = i & 31;
    s4v o = {};
    if (row < N_NODES) {
      float mean = gsums[g] * invc;
      float var = gsums[32 + g] * invc - mean * mean;
      float rs = rsqrtf(var + EPSV);
      s4v v0 = *(const s4v*)(p0 + (size_t)row * CMID + g * 4);
      s4v v1 = *(const s4v*)(p1 + (size_t)row * CMID + g * 4);
      f4v bv = *(const f4v*)(b1 + g * 4);
      f4v wv = *(const f4v*)(gn_w + g * 4);
      f4v gv = *(const f4v*)(gn_b + g * 4);
#pragma unroll
      for (int e = 0; e < 4; ++e) {
        float x = __uint_as_float(((uint32_t)(uint16_t)v0[e]) << 16) +
                  __uint_as_float(((uint32_t)(uint16_t)v1[e]) << 16) + bv[e];
        float xn = (x - mean) * rs * wv[e] + gv[e];
        float y = xn / (1.0f + __expf(-xn));
        o[e] = (short)f2bf(y);
      }
    }
    *(s4v*)(xnb + (size_t)row * CMID + g * 4) = o;   // row N stays zeros
  }
}

// ---------------------------------------------------------------- conv2 -----
// No LDS, no barriers. Wave owns 16 rows x 32 cols. Block = 4 waves = 64 rows.
__global__ __launch_bounds__(256) void k_conv2(
    const short* __restrict__ xnb, const void* __restrict__ neigh,
    const short* __restrict__ wt2f, const float* __restrict__ b2,
    float* __restrict__ out, const int* __restrict__ flag)
{
  const int tid = threadIdx.x;
  const int l = tid & 63;
  const int w = tid >> 6;
  const int r0 = blockIdx.x * 64 + w * 16;
  const bool is64 = (*flag != 0);

  f4v acc[2] = {};
  for (int k = 0; k < KNB; ++k) {
    int i0 = read_idx(neigh, r0 + (l & 15), k, is64);
    const short* ap = xnb + (size_t)i0 * CMID + (l >> 4) * 8;
    s8v a[4];
#pragma unroll
    for (int kc = 0; kc < 4; ++kc) a[kc] = *(const s8v*)(ap + kc * 32);
    const short* wp = wt2f + (size_t)k * 512 * 8;
#pragma unroll
    for (int kc = 0; kc < 4; ++kc) {
#pragma unroll
      for (int n = 0; n < 2; ++n) {
        s8v b = *(const s8v*)(wp + ((kc * 2 + n) * 64 + l) * 8);
        acc[n] = mfma16(a[kc], b, acc[n]);
      }
    }
  }

#pragma unroll
  for (int n = 0; n < 2; ++n) {
    int col = n * 16 + (l & 15);
    float bias = b2[col];
#pragma unroll
    for (int j = 0; j < 4; ++j) {
      int grow = r0 + (l >> 4) * 4 + j;
      if (grow < N_NODES) out[(size_t)grow * COUT + col] = acc[n][j] + bias;
    }
  }
}

// ---------------------------------------------------------------- launch ----
extern "C" void kernel_launch(void* const* d_in, const int* in_sizes, int n_in,
                              void* d_out, int out_size, void* d_ws, size_t ws_size,
                              hipStream_t stream) {
  const float* data = (const float*)d_in[0];
  const void* neigh = d_in[1];
  const float* W1   = (const float*)d_in[2];
  const float* b1   = (const float*)d_in[3];
  const float* gn_w = (const float*)d_in[4];
  const float* gn_b = (const float*)d_in[5];
  const float* W2   = (const float*)d_in[6];
  const float* b2   = (const float*)d_in[7];

  char* p = (char*)d_ws;
  short* xb   = (short*)p; p += (size_t)(N_NODES + 1) * CIN * 2;       // 12.8MB
  short* wt1f = (short*)p; p += (size_t)KNB * CMID * CIN * 2;          // 884KB
  short* wt2f = (short*)p; p += (size_t)KNB * COUT * CMID * 2;         // 221KB
  short* x1p  = (short*)p; p += (size_t)2 * N_NODES * CMID * 2;        // 25.6MB
  short* xnb  = (short*)p; p += (size_t)(N_NODES + 1) * CMID * 2;      // 12.8MB
  float* gsums = (float*)p;                                             // 64 f32
  int* flag = (int*)(gsums + 64);

  k_prep<<<2048, 256, 0, stream>>>(data, W1, W2, (const int*)neigh,
                                   xb, wt1f, wt2f, gsums, flag);
  k_conv1<<<782, 256, 0, stream>>>(xb, neigh, wt1f, x1p, flag);
  k_sum<<<391, 256, 0, stream>>>(x1p, b1, gsums);
  k_gnsilu<<<2048, 256, 0, stream>>>(x1p, b1, gsums, gn_w, gn_b, xnb);
  k_conv2<<<782, 256, 0, stream>>>(xnb, neigh, wt2f, b2, (float*)d_out, flag);
}

// Round 3
// 321.006 us; speedup vs baseline: 3.8893x; 1.1094x over previous
//
#include <hip/hip_runtime.h>
#include <stdint.h>

#define N_NODES 50000
#define CIN 128
#define CMID 128
#define COUT 32
#define KNB 27
#define EPSV 1e-5f

typedef __attribute__((ext_vector_type(4))) float f4v;
typedef __attribute__((ext_vector_type(8))) short s8v;
typedef __attribute__((ext_vector_type(4))) short s4v;

__device__ __forceinline__ unsigned short f2bf(float f) {
  union { float f; uint32_t u; } v; v.f = f;
  return (unsigned short)((v.u + 0x7FFFu + ((v.u >> 16) & 1u)) >> 16);  // RNE
}

__device__ __forceinline__ f4v mfma16(s8v a, s8v b, f4v c) {
  return __builtin_amdgcn_mfma_f32_16x16x32_bf16(a, b, c, 0, 0, 0);
}

// ---------------------------------------------------------------- flag ------
__global__ void k_flag(const int* __restrict__ neigh_raw, int* __restrict__ flag) {
  if (threadIdx.x == 0) {
    int ok = 1;
    for (int i = 0; i < 16; ++i) {
      int hi = neigh_raw[2 * i + 1];
      if (hi != 0 && hi != -1) ok = 0;
    }
    *flag = ok;   // 1 => neigh is int64
  }
}

// ---------------------------------------------------------------- prep ------
// xb[(N+1)][128] bf16 (row N zeros); wt1f/wt2f in MFMA B-fragment order;
// neighT[k][row] int32 (empty -> N_NODES); gsums[0..63]=0
__global__ __launch_bounds__(256) void k_prep(
    const float* __restrict__ data, const float* __restrict__ W1,
    const float* __restrict__ W2, const void* __restrict__ neigh,
    short* __restrict__ xb, short* __restrict__ wt1f, short* __restrict__ wt2f,
    int* __restrict__ neighT, float* __restrict__ gsums,
    const int* __restrict__ flag)
{
  const int TOT0 = (N_NODES + 1) * (CIN / 4);   // xb s4v chunks
  const int TOTW1 = KNB * 4 * 8 * 64;           // wt1f 16B chunks
  const int TOTW2 = KNB * 4 * 2 * 64;           // wt2f 16B chunks
  const int TOT3 = KNB * N_NODES;               // neighT elements
  const bool is64 = (*flag != 0);
  int gtid = blockIdx.x * 256 + threadIdx.x;
  int stride = gridDim.x * 256;
  for (int i = gtid; i < TOT0 + TOTW1 + TOTW2 + TOT3; i += stride) {
    if (i < TOT0) {
      int row = i >> 5, c4 = i & 31;
      s4v o = {};
      if (row < N_NODES) {
        f4v v = *(const f4v*)(data + (size_t)row * CIN + c4 * 4);
        o[0] = (short)f2bf(v[0]); o[1] = (short)f2bf(v[1]);
        o[2] = (short)f2bf(v[2]); o[3] = (short)f2bf(v[3]);
      }
      *(s4v*)(xb + (size_t)row * CIN + c4 * 4) = o;
    } else if (i < TOT0 + TOTW1) {
      int c = i - TOT0;
      int k = c >> 11, rem = c & 2047;
      int kc = rem >> 9, rem2 = rem & 511;
      int n = rem2 >> 6, l = rem2 & 63;
      int cin0 = kc * 32 + (l >> 4) * 8, cout = n * 16 + (l & 15);
      s8v o;
#pragma unroll
      for (int e = 0; e < 8; ++e)
        o[e] = (short)f2bf(W1[(size_t)k * (CIN * CMID) + (cin0 + e) * CMID + cout]);
      *(s8v*)(wt1f + (size_t)c * 8) = o;
    } else if (i < TOT0 + TOTW1 + TOTW2) {
      int c = i - TOT0 - TOTW1;
      int k = c >> 9, rem = c & 511;
      int kc = rem >> 7, rem2 = rem & 127;
      int n = rem2 >> 6, l = rem2 & 63;
      int cin0 = kc * 32 + (l >> 4) * 8, cout = n * 16 + (l & 15);
      s8v o;
#pragma unroll
      for (int e = 0; e < 8; ++e)
        o[e] = (short)f2bf(W2[(size_t)k * (CMID * COUT) + (cin0 + e) * COUT + cout]);
      *(s8v*)(wt2f + (size_t)c * 8) = o;
    } else {
      int c = i - TOT0 - TOTW1 - TOTW2;
      int k = c / N_NODES, r = c - k * N_NODES;
      long long v = is64 ? ((const long long*)neigh)[(size_t)r * KNB + k]
                         : (long long)((const int*)neigh)[(size_t)r * KNB + k];
      neighT[(size_t)k * N_NODES + r] = (v < 0) ? N_NODES : (int)v;
    }
  }
  if (gtid < 64) gsums[gtid] = 0.0f;
}

// ---------------------------------------------------------------- conv1 -----
// Barrier-free implicit GEMM. 2 waves/block, wave = 32 rows x 128 cols,
// K split in 2 halves. Explicit 2-deep pipeline: gather A[k+1] + idx[k+2]
// while MFMA-ing A[k]. launch_bounds(128,2): room for B-load pipelining.
__global__ __launch_bounds__(128, 2) void k_conv1(
    const short* __restrict__ xb, const int* __restrict__ neighT,
    const short* __restrict__ wt1f, short* __restrict__ x1p)
{
  const int tid = threadIdx.x;
  const int l = tid & 63;
  const int w = tid >> 6;
  const int bx = blockIdx.x;
  const int kh = (bx >= 782) ? 1 : 0;
  const int rb = kh ? bx - 782 : bx;
  const int r0 = rb * 64 + w * 32;
  const int k0 = kh ? 13 : 0, k1 = kh ? 27 : 13;
  const int lr = l & 15, lo8 = (l >> 4) * 8;

  int ra = r0 + lr;       if (ra >= N_NODES) ra = N_NODES - 1;
  int rbb = r0 + 16 + lr; if (rbb >= N_NODES) rbb = N_NODES - 1;

  f4v acc[2][8] = {};

  // prologue: gather A[k0], prefetch idx[k0+1]
  int i0 = neighT[(size_t)k0 * N_NODES + ra];
  int i1 = neighT[(size_t)k0 * N_NODES + rbb];
  s8v ac[2][4], an[2][4];
  {
    const short* p0 = xb + (size_t)i0 * CIN + lo8;
    const short* p1 = xb + (size_t)i1 * CIN + lo8;
#pragma unroll
    for (int kc = 0; kc < 4; ++kc) {
      ac[0][kc] = *(const s8v*)(p0 + kc * 32);
      ac[1][kc] = *(const s8v*)(p1 + kc * 32);
    }
  }
  int i0n = 0, i1n = 0;
  if (k0 + 1 < k1) {
    i0n = neighT[(size_t)(k0 + 1) * N_NODES + ra];
    i1n = neighT[(size_t)(k0 + 1) * N_NODES + rbb];
  }

  for (int k = k0; k < k1; ++k) {
    if (k + 1 < k1) {                       // issue next-k gathers early
      const short* p0 = xb + (size_t)i0n * CIN + lo8;
      const short* p1 = xb + (size_t)i1n * CIN + lo8;
#pragma unroll
      for (int kc = 0; kc < 4; ++kc) {
        an[0][kc] = *(const s8v*)(p0 + kc * 32);
        an[1][kc] = *(const s8v*)(p1 + kc * 32);
      }
    }
    if (k + 2 < k1) {                       // idx two ahead (coalesced 64B)
      i0n = neighT[(size_t)(k + 2) * N_NODES + ra];
      i1n = neighT[(size_t)(k + 2) * N_NODES + rbb];
    }
    const short* wp = wt1f + (size_t)k * 16384 + (size_t)l * 8;
#pragma unroll
    for (int kc = 0; kc < 4; ++kc) {
#pragma unroll
      for (int n = 0; n < 8; ++n) {
        s8v b = *(const s8v*)(wp + (kc * 8 + n) * 512);  // coalesced 1KB/instr
        acc[0][n] = mfma16(ac[0][kc], b, acc[0][n]);
        acc[1][n] = mfma16(ac[1][kc], b, acc[1][n]);
      }
    }
#pragma unroll
    for (int kc = 0; kc < 4; ++kc) {        // rotate pipeline regs
      ac[0][kc] = an[0][kc];
      ac[1][kc] = an[1][kc];
    }
  }

  short* xp = x1p + (size_t)kh * N_NODES * CMID;
#pragma unroll
  for (int m = 0; m < 2; ++m) {
#pragma unroll
    for (int j = 0; j < 4; ++j) {
      int grow = r0 + m * 16 + (l >> 4) * 4 + j;
      if (grow < N_NODES) {
#pragma unroll
        for (int n = 0; n < 8; ++n)
          xp[(size_t)grow * CMID + n * 16 + lr] = (short)f2bf(acc[m][n][j]);
      }
    }
  }
}

// ---------------------------------------------------------------- sum -------
__global__ __launch_bounds__(256) void k_sum(
    const short* __restrict__ x1p, const float* __restrict__ b1,
    float* __restrict__ gsums)
{
  __shared__ float sh[64];
  const int tid = threadIdx.x;
  if (tid < 64) sh[tid] = 0.0f;
  __syncthreads();
  const int g = tid & 31;
  const short* p0 = x1p;
  const short* p1 = x1p + (size_t)N_NODES * CMID;
  f4v bv = *(const f4v*)(b1 + g * 4);
  float s = 0.f, ss = 0.f;
  for (int r = blockIdx.x * 8 + (tid >> 5); r < N_NODES; r += gridDim.x * 8) {
    s4v v0 = *(const s4v*)(p0 + (size_t)r * CMID + g * 4);
    s4v v1 = *(const s4v*)(p1 + (size_t)r * CMID + g * 4);
#pragma unroll
    for (int e = 0; e < 4; ++e) {
      float x = __uint_as_float(((uint32_t)(uint16_t)v0[e]) << 16) +
                __uint_as_float(((uint32_t)(uint16_t)v1[e]) << 16) + bv[e];
      s += x; ss += x * x;
    }
  }
  s += __shfl_xor(s, 32); ss += __shfl_xor(ss, 32);
  if ((tid & 32) == 0) { atomicAdd(&sh[g], s); atomicAdd(&sh[32 + g], ss); }
  __syncthreads();
  if (tid < 64) atomicAdd(&gsums[tid], sh[tid]);
}

// ---------------------------------------------------------------- GN+SiLU ---
__global__ __launch_bounds__(256) void k_gnsilu(
    const short* __restrict__ x1p, const float* __restrict__ b1,
    const float* __restrict__ gsums, const float* __restrict__ gn_w,
    const float* __restrict__ gn_b, short* __restrict__ xnb)
{
  const float invc = 1.0f / (N_NODES * 4.0f);
  const short* p0 = x1p;
  const short* p1 = x1p + (size_t)N_NODES * CMID;
  int gtid = blockIdx.x * 256 + threadIdx.x;
  int stride = gridDim.x * 256;
  const int TOT = (N_NODES + 1) * (CMID / 4);
  for (int i = gtid; i < TOT; i += stride) {
    int row = i >> 5, g = i & 31;
    s4v o = {};
    if (row < N_NODES) {
      float mean = gsums[g] * invc;
      float var = gsums[32 + g] * invc - mean * mean;
      float rs = rsqrtf(var + EPSV);
      s4v v0 = *(const s4v*)(p0 + (size_t)row * CMID + g * 4);
      s4v v1 = *(const s4v*)(p1 + (size_t)row * CMID + g * 4);
      f4v bv = *(const f4v*)(b1 + g * 4);
      f4v wv = *(const f4v*)(gn_w + g * 4);
      f4v gv = *(const f4v*)(gn_b + g * 4);
#pragma unroll
      for (int e = 0; e < 4; ++e) {
        float x = __uint_as_float(((uint32_t)(uint16_t)v0[e]) << 16) +
                  __uint_as_float(((uint32_t)(uint16_t)v1[e]) << 16) + bv[e];
        float xn = (x - mean) * rs * wv[e] + gv[e];
        float y = xn / (1.0f + __expf(-xn));
        o[e] = (short)f2bf(y);
      }
    }
    *(s4v*)(xnb + (size_t)row * CMID + g * 4) = o;
  }
}

// ---------------------------------------------------------------- conv2 -----
// Barrier-free, 2 waves/block, wave = 16 rows x 32 cols, full K, 2-deep pipeline.
__global__ __launch_bounds__(128, 4) void k_conv2(
    const short* __restrict__ xnb, const int* __restrict__ neighT,
    const short* __restrict__ wt2f, const float* __restrict__ b2,
    float* __restrict__ out)
{
  const int tid = threadIdx.x;
  const int l = tid & 63;
  const int w = tid >> 6;
  const int r0 = blockIdx.x * 32 + w * 16;
  const int lr = l & 15, lo8 = (l >> 4) * 8;
  int ra = r0 + lr; if (ra >= N_NODES) ra = N_NODES - 1;

  f4v acc[2] = {};
  int i0 = neighT[ra];
  s8v ac[4], an[4];
  {
    const short* p0 = xnb + (size_t)i0 * CMID + lo8;
#pragma unroll
    for (int kc = 0; kc < 4; ++kc) ac[kc] = *(const s8v*)(p0 + kc * 32);
  }
  int i0n = neighT[(size_t)1 * N_NODES + ra];

  for (int k = 0; k < KNB; ++k) {
    if (k + 1 < KNB) {
      const short* p0 = xnb + (size_t)i0n * CMID + lo8;
#pragma unroll
      for (int kc = 0; kc < 4; ++kc) an[kc] = *(const s8v*)(p0 + kc * 32);
    }
    if (k + 2 < KNB) i0n = neighT[(size_t)(k + 2) * N_NODES + ra];
    const short* wp = wt2f + (size_t)k * 4096 + (size_t)l * 8;
#pragma unroll
    for (int kc = 0; kc < 4; ++kc) {
#pragma unroll
      for (int n = 0; n < 2; ++n) {
        s8v b = *(const s8v*)(wp + (kc * 2 + n) * 512);
        acc[n] = mfma16(ac[kc], b, acc[n]);
      }
    }
#pragma unroll
    for (int kc = 0; kc < 4; ++kc) ac[kc] = an[kc];
  }

#pragma unroll
  for (int n = 0; n < 2; ++n) {
    int col = n * 16 + lr;
    float bias = b2[col];
#pragma unroll
    for (int j = 0; j < 4; ++j) {
      int grow = r0 + (l >> 4) * 4 + j;
      if (grow < N_NODES) out[(size_t)grow * COUT + col] = acc[n][j] + bias;
    }
  }
}

// ---------------------------------------------------------------- launch ----
extern "C" void kernel_launch(void* const* d_in, const int* in_sizes, int n_in,
                              void* d_out, int out_size, void* d_ws, size_t ws_size,
                              hipStream_t stream) {
  const float* data = (const float*)d_in[0];
  const void* neigh = d_in[1];
  const float* W1   = (const float*)d_in[2];
  const float* b1   = (const float*)d_in[3];
  const float* gn_w = (const float*)d_in[4];
  const float* gn_b = (const float*)d_in[5];
  const float* W2   = (const float*)d_in[6];
  const float* b2   = (const float*)d_in[7];

  char* p = (char*)d_ws;
  short* xb   = (short*)p; p += (size_t)(N_NODES + 1) * CIN * 2;       // 12.8MB
  short* wt1f = (short*)p; p += (size_t)KNB * CMID * CIN * 2;          // 884KB
  short* wt2f = (short*)p; p += (size_t)KNB * COUT * CMID * 2;         // 221KB
  short* x1p  = (short*)p; p += (size_t)2 * N_NODES * CMID * 2;        // 25.6MB
  short* xnb  = (short*)p; p += (size_t)(N_NODES + 1) * CMID * 2;      // 12.8MB
  int*   neighT = (int*)p; p += (size_t)KNB * N_NODES * 4;             // 5.4MB
  float* gsums = (float*)p;                                             // 64 f32
  int* flag = (int*)(gsums + 64);

  k_flag<<<1, 64, 0, stream>>>((const int*)neigh, flag);
  k_prep<<<2048, 256, 0, stream>>>(data, W1, W2, neigh,
                                   xb, wt1f, wt2f, neighT, gsums, flag);
  k_conv1<<<1564, 128, 0, stream>>>(xb, neighT, wt1f, x1p);
  k_sum<<<391, 256, 0, stream>>>(x1p, b1, gsums);
  k_gnsilu<<<2048, 256, 0, stream>>>(x1p, b1, gsums, gn_w, gn_b, xnb);
  k_conv2<<<1563, 128, 0, stream>>>(xnb, neighT, wt2f, b2, (float*)d_out);
}

// Round 4
// 234.488 us; speedup vs baseline: 5.3244x; 1.3690x over previous
//
#include <hip/hip_runtime.h>
#include <stdint.h>

#define N_NODES 50000
#define CIN 128
#define CMID 128
#define COUT 32
#define KNB 27
#define EPSV 1e-5f

typedef __attribute__((ext_vector_type(4))) float f4v;
typedef __attribute__((ext_vector_type(8))) short s8v;
typedef __attribute__((ext_vector_type(4))) short s4v;

__device__ __forceinline__ unsigned short f2bf(float f) {
  union { float f; uint32_t u; } v; v.f = f;
  return (unsigned short)((v.u + 0x7FFFu + ((v.u >> 16) & 1u)) >> 16);  // RNE
}

__device__ __forceinline__ f4v mfma16(s8v a, s8v b, f4v c) {
  return __builtin_amdgcn_mfma_f32_16x16x32_bf16(a, b, c, 0, 0, 0);
}

// async global->LDS, 16B/lane; dest wave-uniform base + lane*16, src per-lane.
__device__ __forceinline__ void gload_lds16(const void* g, void* lds) {
  __builtin_amdgcn_global_load_lds(
      (const __attribute__((address_space(1))) uint32_t*)(uintptr_t)g,
      (__attribute__((address_space(3))) uint32_t*)(uint32_t)(uintptr_t)lds,
      16, 0, 0);
}

// ---------------------------------------------------------------- flag ------
__global__ void k_flag(const int* __restrict__ neigh_raw, int* __restrict__ flag) {
  if (threadIdx.x == 0) {
    int ok = 1;
    for (int i = 0; i < 16; ++i) {
      int hi = neigh_raw[2 * i + 1];
      if (hi != 0 && hi != -1) ok = 0;
    }
    *flag = ok;   // 1 => neigh is int64
  }
}

// ---------------------------------------------------------------- transpose -
// neighT[k][row] int32 (empty -> N_NODES), via LDS tile transpose (coalesced).
__global__ __launch_bounds__(256) void k_transpose(
    const void* __restrict__ neigh, int* __restrict__ neighT,
    const int* __restrict__ flag)
{
  __shared__ int tT[KNB][257];
  const int r0 = blockIdx.x * 256;
  const bool is64 = (*flag != 0);
  const int tid = threadIdx.x;
  for (int e = tid; e < 256 * KNB; e += 256) {
    int r = e / KNB, k = e - r * KNB;
    if (r0 + r < N_NODES) {
      long long v = is64 ? ((const long long*)neigh)[(size_t)r0 * KNB + e]
                         : (long long)((const int*)neigh)[(size_t)r0 * KNB + e];
      tT[k][r] = (v < 0) ? N_NODES : (int)v;
    }
  }
  __syncthreads();
  for (int e = tid; e < KNB * 256; e += 256) {
    int k = e >> 8, r = e & 255;
    if (r0 + r < N_NODES) neighT[(size_t)k * N_NODES + r0 + r] = tT[k][r];
  }
}

// ---------------------------------------------------------------- prep ------
// xb[(N+1)][128] bf16 (row N zeros); wt1f/wt2f in MFMA B-fragment order:
//   wt1f chunk ((k*4+kc)*8+n)*64+l = 8 bf16 {W1[k][kc*32+(l>>4)*8+e][n*16+(l&15)]}
//   wt2f chunk ((k*4+kc)*2+n)*64+l = 8 bf16 {W2[k][kc*32+(l>>4)*8+e][n*16+(l&15)]}
__global__ __launch_bounds__(256) void k_prep(
    const float* __restrict__ data, const float* __restrict__ W1,
    const float* __restrict__ W2,
    short* __restrict__ xb, short* __restrict__ wt1f, short* __restrict__ wt2f,
    float* __restrict__ gsums)
{
  const int TOT0 = (N_NODES + 1) * (CIN / 4);
  const int TOTW1 = KNB * 4 * 8 * 64;
  const int TOTW2 = KNB * 4 * 2 * 64;
  int gtid = blockIdx.x * 256 + threadIdx.x;
  int stride = gridDim.x * 256;
  for (int i = gtid; i < TOT0 + TOTW1 + TOTW2; i += stride) {
    if (i < TOT0) {
      int row = i >> 5, c4 = i & 31;
      s4v o = {};
      if (row < N_NODES) {
        f4v v = *(const f4v*)(data + (size_t)row * CIN + c4 * 4);
        o[0] = (short)f2bf(v[0]); o[1] = (short)f2bf(v[1]);
        o[2] = (short)f2bf(v[2]); o[3] = (short)f2bf(v[3]);
      }
      *(s4v*)(xb + (size_t)row * CIN + c4 * 4) = o;
    } else if (i < TOT0 + TOTW1) {
      int c = i - TOT0;
      int k = c >> 11, rem = c & 2047;
      int kc = rem >> 9, rem2 = rem & 511;
      int n = rem2 >> 6, l = rem2 & 63;
      int cin0 = kc * 32 + (l >> 4) * 8, cout = n * 16 + (l & 15);
      s8v o;
#pragma unroll
      for (int e = 0; e < 8; ++e)
        o[e] = (short)f2bf(W1[(size_t)k * (CIN * CMID) + (cin0 + e) * CMID + cout]);
      *(s8v*)(wt1f + (size_t)c * 8) = o;
    } else {
      int c = i - TOT0 - TOTW1;
      int k = c >> 9, rem = c & 511;
      int kc = rem >> 7, rem2 = rem & 127;
      int n = rem2 >> 6, l = rem2 & 63;
      int cin0 = kc * 32 + (l >> 4) * 8, cout = n * 16 + (l & 15);
      s8v o;
#pragma unroll
      for (int e = 0; e < 8; ++e)
        o[e] = (short)f2bf(W2[(size_t)k * (CMID * COUT) + (cin0 + e) * COUT + cout]);
      *(s8v*)(wt2f + (size_t)c * 8) = o;
    }
  }
  if (gtid < 64) gsums[gtid] = 0.0f;
}

// ---------------------------------------------------------------- conv1 -----
// M_block=128, 4 waves (wave = 32 rows x 128 cols), BK=64 (half k-neighbor),
// kh-split 2. B: LDS dbuf via global_load_lds (contiguous fragment order).
// A: gather->regs, ds_write to wave-PRIVATE LDS region (XOR swizzle slot^row&7
// both sides). One barrier per step; stage s+1 overlaps compute s.
__global__ __launch_bounds__(256, 2) void k_conv1(
    const short* __restrict__ xb, const int* __restrict__ neighT,
    const short* __restrict__ wt1f, short* __restrict__ x1p)
{
  __shared__ short Bs[2][8192];        // 2 x 16KB
  __shared__ short As[4][2][2048];     // per-wave 2 x 4KB (32 rows x 128B)
  const int tid = threadIdx.x;
  const int l = tid & 63, w = tid >> 6;
  const int bx = blockIdx.x;
  const int kh = (bx >= 391) ? 1 : 0;
  const int rb = kh ? bx - 391 : bx;
  const int rw = rb * 128 + w * 32;    // wave's first row
  const int k0 = kh ? 13 : 0, k1 = kh ? 27 : 13;
  const int lr = l & 15, lho = l >> 4; // frag row / 8-elem group
  const int l8 = l >> 3, ls = l & 7;   // gather: row-in-8 / 16B slot

  f4v acc[2][8] = {};
  int idx[4], idxn[4];
  s8v ga[4];

  auto loadIdx = [&](int* id, int k) {
#pragma unroll
    for (int q = 0; q < 4; ++q) {
      int r = rw + q * 8 + l8; if (r >= N_NODES) r = N_NODES - 1;
      id[q] = neighT[(size_t)k * N_NODES + r];
    }
  };
  auto stageB = [&](int buf, int k, int h) {
    const short* src = wt1f + ((size_t)(k * 4 + h * 2) * 8) * 512 + l * 8;
#pragma unroll
    for (int j = 0; j < 4; ++j)
      gload_lds16(src + (w * 4 + j) * 512, &Bs[buf][(w * 4 + j) * 512]);
  };
  auto gatherA = [&](const int* id, int h) {
#pragma unroll
    for (int q = 0; q < 4; ++q)
      ga[q] = *(const s8v*)(xb + (size_t)id[q] * CIN + h * 64 + ls * 8);
  };
  auto writeA = [&](int buf) {
#pragma unroll
    for (int q = 0; q < 4; ++q)
      *(s8v*)&As[w][buf][(q * 8 + l8) * 64 + ((ls ^ l8) * 8)] = ga[q];
  };
  auto compute = [&](int cb) {
#pragma unroll
    for (int kc = 0; kc < 2; ++kc) {
      s8v af[2];
#pragma unroll
      for (int rg = 0; rg < 2; ++rg) {
        int row = rg * 16 + lr;
        af[rg] = *(const s8v*)&As[w][cb][row * 64 + (((kc * 4 + lho) ^ (lr & 7)) * 8)];
      }
#pragma unroll
      for (int n = 0; n < 8; ++n) {
        s8v bf = *(const s8v*)&Bs[cb][(kc * 8 + n) * 512 + l * 8];
        acc[0][n] = mfma16(af[0], bf, acc[0][n]);
        acc[1][n] = mfma16(af[1], bf, acc[1][n]);
      }
    }
  };

  // prologue: step (k0, h=0) into buf 0
  loadIdx(idx, k0);
  stageB(0, k0, 0);
  gatherA(idx, 0);
  __syncthreads();
  writeA(0);

  int cur = 0;
  for (int k = k0; k < k1; ++k) {
    const bool more = (k + 1 < k1);
    // --- step h=0: compute buf cur, prefetch (k, h=1)
    stageB(cur ^ 1, k, 1);
    gatherA(idx, 1);
    if (more) loadIdx(idxn, k + 1);
    compute(cur);
    __syncthreads();
    writeA(cur ^ 1);
    cur ^= 1;
    // --- step h=1: compute buf cur, prefetch (k+1, h=0)
    if (more) { stageB(cur ^ 1, k + 1, 0); gatherA(idxn, 0); }
    compute(cur);
    __syncthreads();
    if (more) {
      writeA(cur ^ 1);
#pragma unroll
      for (int q = 0; q < 4; ++q) idx[q] = idxn[q];
    }
    cur ^= 1;
  }

  // epilogue: bf16 partial
  short* xp = x1p + (size_t)kh * N_NODES * CMID;
#pragma unroll
  for (int rg = 0; rg < 2; ++rg) {
#pragma unroll
    for (int j = 0; j < 4; ++j) {
      int grow = rw + rg * 16 + lho * 4 + j;
      if (grow < N_NODES) {
#pragma unroll
        for (int n = 0; n < 8; ++n)
          xp[(size_t)grow * CMID + n * 16 + lr] = (short)f2bf(acc[rg][n][j]);
      }
    }
  }
}

// ---------------------------------------------------------------- sum -------
__global__ __launch_bounds__(256) void k_sum(
    const short* __restrict__ x1p, const float* __restrict__ b1,
    float* __restrict__ gsums)
{
  __shared__ float sh[64];
  const int tid = threadIdx.x;
  if (tid < 64) sh[tid] = 0.0f;
  __syncthreads();
  const int g = tid & 31;
  const short* p0 = x1p;
  const short* p1 = x1p + (size_t)N_NODES * CMID;
  f4v bv = *(const f4v*)(b1 + g * 4);
  float s = 0.f, ss = 0.f;
  for (int r = blockIdx.x * 8 + (tid >> 5); r < N_NODES; r += gridDim.x * 8) {
    s4v v0 = *(const s4v*)(p0 + (size_t)r * CMID + g * 4);
    s4v v1 = *(const s4v*)(p1 + (size_t)r * CMID + g * 4);
#pragma unroll
    for (int e = 0; e < 4; ++e) {
      float x = __uint_as_float(((uint32_t)(uint16_t)v0[e]) << 16) +
                __uint_as_float(((uint32_t)(uint16_t)v1[e]) << 16) + bv[e];
      s += x; ss += x * x;
    }
  }
  s += __shfl_xor(s, 32); ss += __shfl_xor(ss, 32);
  if ((tid & 32) == 0) { atomicAdd(&sh[g], s); atomicAdd(&sh[32 + g], ss); }
  __syncthreads();
  if (tid < 64) atomicAdd(&gsums[tid], sh[tid]);
}

// ---------------------------------------------------------------- GN+SiLU ---
__global__ __launch_bounds__(256) void k_gnsilu(
    const short* __restrict__ x1p, const float* __restrict__ b1,
    const float* __restrict__ gsums, const float* __restrict__ gn_w,
    const float* __restrict__ gn_b, short* __restrict__ xnb)
{
  const float invc = 1.0f / (N_NODES * 4.0f);
  const short* p0 = x1p;
  const short* p1 = x1p + (size_t)N_NODES * CMID;
  int gtid = blockIdx.x * 256 + threadIdx.x;
  int stride = gridDim.x * 256;
  const int TOT = (N_NODES + 1) * (CMID / 4);
  for (int i = gtid; i < TOT; i += stride) {
    int row = i >> 5, g = i & 31;
    s4v o = {};
    if (row < N_NODES) {
      float mean = gsums[g] * invc;
      float var = gsums[32 + g] * invc - mean * mean;
      float rs = rsqrtf(var + EPSV);
      s4v v0 = *(const s4v*)(p0 + (size_t)row * CMID + g * 4);
      s4v v1 = *(const s4v*)(p1 + (size_t)row * CMID + g * 4);
      f4v bv = *(const f4v*)(b1 + g * 4);
      f4v wv = *(const f4v*)(gn_w + g * 4);
      f4v gv = *(const f4v*)(gn_b + g * 4);
#pragma unroll
      for (int e = 0; e < 4; ++e) {
        float x = __uint_as_float(((uint32_t)(uint16_t)v0[e]) << 16) +
                  __uint_as_float(((uint32_t)(uint16_t)v1[e]) << 16) + bv[e];
        float xn = (x - mean) * rs * wv[e] + gv[e];
        float y = xn / (1.0f + __expf(-xn));
        o[e] = (short)f2bf(y);
      }
    }
    *(s4v*)(xnb + (size_t)row * CMID + g * 4) = o;
  }
}

// ---------------------------------------------------------------- conv2 -----
// Same template: M_block=128, wave = 32 rows x 32 cols, BK=64, kh-split 2.
// f32 partials (combined with bias in k_fin).
__global__ __launch_bounds__(256, 4) void k_conv2(
    const short* __restrict__ xnb, const int* __restrict__ neighT,
    const short* __restrict__ wt2f, float* __restrict__ x2p)
{
  __shared__ short Bs[2][2048];        // 2 x 4KB
  __shared__ short As[4][2][2048];
  const int tid = threadIdx.x;
  const int l = tid & 63, w = tid >> 6;
  const int bx = blockIdx.x;
  const int kh = (bx >= 391) ? 1 : 0;
  const int rb = kh ? bx - 391 : bx;
  const int rw = rb * 128 + w * 32;
  const int k0 = kh ? 13 : 0, k1 = kh ? 27 : 13;
  const int lr = l & 15, lho = l >> 4;
  const int l8 = l >> 3, ls = l & 7;

  f4v acc[2][2] = {};
  int idx[4], idxn[4];
  s8v ga[4];

  auto loadIdx = [&](int* id, int k) {
#pragma unroll
    for (int q = 0; q < 4; ++q) {
      int r = rw + q * 8 + l8; if (r >= N_NODES) r = N_NODES - 1;
      id[q] = neighT[(size_t)k * N_NODES + r];
    }
  };
  auto stageB = [&](int buf, int k, int h) {
    const short* src = wt2f + ((size_t)(k * 4 + h * 2) * 2) * 512 + l * 8;
    gload_lds16(src + w * 512, &Bs[buf][w * 512]);
  };
  auto gatherA = [&](const int* id, int h) {
#pragma unroll
    for (int q = 0; q < 4; ++q)
      ga[q] = *(const s8v*)(xnb + (size_t)id[q] * CMID + h * 64 + ls * 8);
  };
  auto writeA = [&](int buf) {
#pragma unroll
    for (int q = 0; q < 4; ++q)
      *(s8v*)&As[w][buf][(q * 8 + l8) * 64 + ((ls ^ l8) * 8)] = ga[q];
  };
  auto compute = [&](int cb) {
#pragma unroll
    for (int kc = 0; kc < 2; ++kc) {
      s8v af[2];
#pragma unroll
      for (int rg = 0; rg < 2; ++rg) {
        int row = rg * 16 + lr;
        af[rg] = *(const s8v*)&As[w][cb][row * 64 + (((kc * 4 + lho) ^ (lr & 7)) * 8)];
      }
#pragma unroll
      for (int n = 0; n < 2; ++n) {
        s8v bf = *(const s8v*)&Bs[cb][(kc * 2 + n) * 512 + l * 8];
        acc[0][n] = mfma16(af[0], bf, acc[0][n]);
        acc[1][n] = mfma16(af[1], bf, acc[1][n]);
      }
    }
  };

  loadIdx(idx, k0);
  stageB(0, k0, 0);
  gatherA(idx, 0);
  __syncthreads();
  writeA(0);

  int cur = 0;
  for (int k = k0; k < k1; ++k) {
    const bool more = (k + 1 < k1);
    stageB(cur ^ 1, k, 1);
    gatherA(idx, 1);
    if (more) loadIdx(idxn, k + 1);
    compute(cur);
    __syncthreads();
    writeA(cur ^ 1);
    cur ^= 1;
    if (more) { stageB(cur ^ 1, k + 1, 0); gatherA(idxn, 0); }
    compute(cur);
    __syncthreads();
    if (more) {
      writeA(cur ^ 1);
#pragma unroll
      for (int q = 0; q < 4; ++q) idx[q] = idxn[q];
    }
    cur ^= 1;
  }

  float* xp = x2p + (size_t)kh * N_NODES * COUT;
#pragma unroll
  for (int rg = 0; rg < 2; ++rg) {
#pragma unroll
    for (int j = 0; j < 4; ++j) {
      int grow = rw + rg * 16 + lho * 4 + j;
      if (grow < N_NODES) {
#pragma unroll
        for (int n = 0; n < 2; ++n)
          xp[(size_t)grow * COUT + n * 16 + lr] = acc[rg][n][j];
      }
    }
  }
}

// ---------------------------------------------------------------- fin -------
__global__ __launch_bounds__(256) void k_fin(
    const float* __restrict__ x2p, const float* __restrict__ b2,
    float* __restrict__ out)
{
  int i = blockIdx.x * 256 + threadIdx.x;          // f4 chunks
  const int TOT = N_NODES * COUT / 4;              // 400000
  if (i < TOT) {
    int c4 = i & 7;
    f4v a = *(const f4v*)(x2p + (size_t)i * 4);
    f4v b = *(const f4v*)(x2p + (size_t)N_NODES * COUT + (size_t)i * 4);
    f4v bias = *(const f4v*)(b2 + c4 * 4);
    f4v o = a + b + bias;
    *(f4v*)(out + (size_t)i * 4) = o;
  }
}

// ---------------------------------------------------------------- launch ----
extern "C" void kernel_launch(void* const* d_in, const int* in_sizes, int n_in,
                              void* d_out, int out_size, void* d_ws, size_t ws_size,
                              hipStream_t stream) {
  const float* data = (const float*)d_in[0];
  const void* neigh = d_in[1];
  const float* W1   = (const float*)d_in[2];
  const float* b1   = (const float*)d_in[3];
  const float* gn_w = (const float*)d_in[4];
  const float* gn_b = (const float*)d_in[5];
  const float* W2   = (const float*)d_in[6];
  const float* b2   = (const float*)d_in[7];

  char* p = (char*)d_ws;
  short* xb   = (short*)p; p += (size_t)(N_NODES + 1) * CIN * 2;   // 12.8MB
  float* x2p  = (float*)xb;                 // alias: xb dead before conv2
  short* wt1f = (short*)p; p += (size_t)KNB * CMID * CIN * 2;      // 884KB
  short* wt2f = (short*)p; p += (size_t)KNB * COUT * CMID * 2;     // 221KB
  short* x1p  = (short*)p; p += (size_t)2 * N_NODES * CMID * 2;    // 25.6MB
  short* xnb  = (short*)p; p += (size_t)(N_NODES + 1) * CMID * 2;  // 12.8MB
  int*   neighT = (int*)p; p += (size_t)KNB * N_NODES * 4;         // 5.4MB
  float* gsums = (float*)p;
  int* flag = (int*)(gsums + 64);

  k_flag<<<1, 64, 0, stream>>>((const int*)neigh, flag);
  k_transpose<<<(N_NODES + 255) / 256, 256, 0, stream>>>(neigh, neighT, flag);
  k_prep<<<2048, 256, 0, stream>>>(data, W1, W2, xb, wt1f, wt2f, gsums);
  k_conv1<<<782, 256, 0, stream>>>(xb, neighT, wt1f, x1p);
  k_sum<<<391, 256, 0, stream>>>(x1p, b1, gsums);
  k_gnsilu<<<2048, 256, 0, stream>>>(x1p, b1, gsums, gn_w, gn_b, xnb);
  k_conv2<<<782, 256, 0, stream>>>(xnb, neighT, wt2f, x2p);
  k_fin<<<(N_NODES * COUT / 4 + 255) / 256, 256, 0, stream>>>(x2p, b2, (float*)d_out);
}